// Round 8
// baseline (614.580 us; speedup 1.0000x reference)
//
#include <hip/hip_runtime.h>
#include <hip/hip_bf16.h>
#include <math.h>

#define BB 16
#define TT 512
#define NN 128
#define PREDN 256
#define DMC 32
#define LL 768
constexpr float EPSF = 1e-5f;

// ---------------- K_pre: blocks 0..63 = partial stats over t-quarters; block 64 = weight fold ----------------
__global__ void k_pre(const float* __restrict__ bx, const float* __restrict__ v0,
                      const float* __restrict__ v1, float* __restrict__ sp,
                      float* __restrict__ s2p, float* __restrict__ vwsT){
  int blk = blockIdx.x;
  if(blk == 64){
    for(int i=threadIdx.x; i<9*DMC; i+=blockDim.x){
      int tap = i/DMC, c = i%DMC;
      float wv = 0.5f*v1[c*9 + tap];
      if(tap == 4) wv += 0.5f*v0[c];
      vwsT[i] = wv;
    }
    return;
  }
  int b = blk >> 2, tq = blk & 3, n = threadIdx.x;
  const float* p = bx + (size_t)b*TT*NN + (size_t)tq*128*NN + n;
  float s = 0.f, s2 = 0.f;
  for(int t=0;t<128;t++){ float v = p[(size_t)t*NN]; s += v; s2 += v*v; }
  sp[tq*2048 + b*NN + n] = s;
  s2p[tq*2048 + b*NN + n] = s2;
}

// ---------------- K1: tiled GEMM1 with fused normalization + dual store ----------------
__global__ __launch_bounds__(256) void k_gemm1(const float* __restrict__ bx, const float* __restrict__ lew,
    const float* __restrict__ leb, const float* __restrict__ sp, const float* __restrict__ s2p,
    float* __restrict__ x, float* __restrict__ a0){
  __shared__ alignas(16) float As[16][68];
  __shared__ alignas(16) float Bs[16][68];
  int tid = threadIdx.x;
  int row0 = blockIdx.x*64, l0 = blockIdx.y*64;
  int b = row0 >> 7, n0 = row0 & 127;
  float acc[4][4] = {};
  int ar = tid & 63, ak = tid >> 6;
  int bk = tid & 15, bc = tid >> 4;
  int tr = tid & 15, tc = tid >> 4;
  int rowa = row0 + ar;
  float ssum = 0.f, s2sum = 0.f;
  #pragma unroll
  for(int tq=0;tq<4;tq++){ ssum += sp[tq*2048 + rowa]; s2sum += s2p[tq*2048 + rowa]; }
  float mu_a = ssum*(1.f/512.f);
  float rs_a = 1.f/sqrtf(fmaxf(s2sum*(1.f/512.f) - mu_a*mu_a, 0.f) + EPSF);
  for(int k0=0;k0<TT;k0+=16){
    #pragma unroll
    for(int q=0;q<4;q++){
      int k = ak*4 + q;
      As[k][ar] = (bx[((size_t)b*TT + k0 + k)*NN + n0 + ar] - mu_a)*rs_a;
    }
    #pragma unroll
    for(int q=0;q<4;q++){
      int c = bc + 16*q;
      Bs[bk][c] = lew[(size_t)(l0+c)*TT + k0 + bk];
    }
    __syncthreads();
    #pragma unroll
    for(int kk=0;kk<16;kk++){
      float4 av = *(const float4*)&As[kk][4*tr];
      float4 bv = *(const float4*)&Bs[kk][4*tc];
      float aa[4] = {av.x, av.y, av.z, av.w};
      float bb[4] = {bv.x, bv.y, bv.z, bv.w};
      #pragma unroll
      for(int i=0;i<4;i++)
        #pragma unroll
        for(int j=0;j<4;j++) acc[i][j] = fmaf(aa[i], bb[j], acc[i][j]);
    }
    __syncthreads();
  }
  #pragma unroll
  for(int i=0;i<4;i++){
    int row = row0 + 4*tr + i;
    int l = l0 + 4*tc;
    float4 st;
    st.x = acc[i][0] + leb[l+0];
    st.y = acc[i][1] + leb[l+1];
    st.z = acc[i][2] + leb[l+2];
    st.w = acc[i][3] + leb[l+3];
    *(float4*)&x[(size_t)row*LL + l] = st;
  }
  #pragma unroll
  for(int j=0;j<4;j++){
    int l = l0 + 4*tc + j;
    float lb = leb[l];
    float4 st;
    st.x = acc[0][j] + lb;
    st.y = acc[1][j] + lb;
    st.z = acc[2][j] + lb;
    st.w = acc[3][j] + lb;
    *(float4*)&a0[((size_t)b*3*LL + l)*NN + n0 + 4*tr] = st;
  }
}

// ---------------- K_conv1g: conv1 as GEMM -> t1b[b][j][o] ----------------
// C[j][o] = sum_K x[b][ci][12j+kk] * w[o][K], K = ci*12+kk (1536)
__global__ __launch_bounds__(256) void k_conv1g(const float* __restrict__ x, const float* __restrict__ w,
    const float* __restrict__ bias, float* __restrict__ t1b){
  __shared__ alignas(16) float As[16][68];  // [k][o']
  __shared__ alignas(16) float Bs[16][68];  // [k][j']
  int tid = threadIdx.x;
  int b = blockIdx.x, o0 = blockIdx.y*64;
  float acc[4][4] = {};
  int ar = tid & 63, ak = tid >> 6;
  int bk = tid & 15, bc = tid >> 4;
  int tr = tid & 15, tc = tid >> 4;
  const float* xb = x + (size_t)b*NN*LL;
  for(int k0=0;k0<1536;k0+=16){
    #pragma unroll
    for(int q=0;q<4;q++){
      int k = ak*4 + q, K = k0 + k;
      int ci = K/12, kk = K - ci*12;
      Bs[k][ar] = xb[(size_t)ci*LL + 12*ar + kk];
    }
    #pragma unroll
    for(int q=0;q<4;q++){
      int oo = bc + 16*q;
      As[bk][oo] = w[(size_t)(o0+oo)*1536 + k0 + bk];
    }
    __syncthreads();
    #pragma unroll
    for(int kk2=0;kk2<16;kk2++){
      float4 av = *(const float4*)&Bs[kk2][4*tr];
      float4 bv = *(const float4*)&As[kk2][4*tc];
      float aa[4] = {av.x, av.y, av.z, av.w};
      float bb[4] = {bv.x, bv.y, bv.z, bv.w};
      #pragma unroll
      for(int i=0;i<4;i++)
        #pragma unroll
        for(int j=0;j<4;j++) acc[i][j] = fmaf(aa[i], bb[j], acc[i][j]);
    }
    __syncthreads();
  }
  #pragma unroll
  for(int i=0;i<4;i++){
    int j = 4*tr + i;
    int o = o0 + 4*tc;
    float4 st;
    st.x = acc[i][0] + bias[o+0];
    st.y = acc[i][1] + bias[o+1];
    st.z = acc[i][2] + bias[o+2];
    st.w = acc[i][3] + bias[o+3];
    *(float4*)&t1b[((size_t)b*64 + j)*NN + o] = st;
  }
}

// ---------------- K_mid2: BN1 + ELU + spline solve64 + eval64 (block per b) ----------------
__global__ __launch_bounds__(256) void k_mid2(const float* __restrict__ t1b, const float* __restrict__ g,
    const float* __restrict__ bb, float* __restrict__ t1tg, float* __restrict__ a){
  __shared__ float yL[64][128];     // 32 KB
  __shared__ float dpM[62*128];     // 31.75 KB (also stats scratch)
  __shared__ float cp[62];
  int b = blockIdx.x, tid = threadIdx.x;
  int o = tid & 127, h = tid >> 7;
  if(tid == 0){
    float cv = 0.25f; cp[0] = cv;
    for(int i=1;i<62;i++){ cv = 1.f/(4.f - cv); cp[i] = cv; }
  }
  // stats over all 1024 (b,j) rows
  float s = 0.f, s2 = 0.f;
  for(int r=h*512; r<h*512+512; r++){
    float v = t1b[(size_t)r*NN + o];
    s += v; s2 += v*v;
  }
  dpM[h*128 + o] = s; dpM[256 + h*128 + o] = s2;
  __syncthreads();
  float stot = dpM[o] + dpM[128+o], s2tot = dpM[256+o] + dpM[384+o];
  float mu = stot*(1.f/1024.f);
  float var = fmaxf(s2tot*(1.f/1024.f) - mu*mu, 0.f);
  float sc = g[o]*rsqrtf(var + EPSF);
  float sh = bb[o] - mu*sc;
  __syncthreads();
  // transform: 32 j's per thread
  for(int j=h*32; j<h*32+32; j++){
    float v = t1b[((size_t)b*64 + j)*NN + o]*sc + sh;
    v = v > 0.f ? v : (expf(v) - 1.f);
    yL[j][o] = v;
    t1tg[((size_t)b*64 + j)*NN + o] = v;
  }
  __syncthreads();
  // Thomas solve (threads 0..127)
  if(h == 0){
    const float Kc = 6.f*63.f*63.f;
    float y0 = yL[0][o], y1 = yL[1][o], dprev = 0.f;
    for(int i=0;i<62;i++){
      float y2 = yL[i+2][o];
      float r = (y2 - 2.f*y1 + y0)*Kc;
      float d = (i == 0) ? r*0.25f : (r - dprev)*cp[i];
      dpM[i*128 + o] = d; dprev = d;
      y0 = y1; y1 = y2;
    }
    float xv = dpM[61*128 + o];   // M[62] = d[61] (in place)
    for(int i=60;i>=0;i--){
      xv = dpM[i*128 + o] - cp[i]*xv;
      dpM[i*128 + o] = xv;        // slot i holds M[i+1]
    }
  }
  __syncthreads();
  // eval: 384 l's per thread
  const float hh = 1.f/63.f, hh6 = hh*hh/6.f;
  float* adst = a + ((size_t)b*3 + 1)*LL*NN;
  for(int l=h*384; l<h*384+384; l++){
    float q = (float)l*(1.f/767.f);
    int idx = (int)floorf(q*63.f); if(idx > 62) idx = 62;
    float sV = q - idx*hh, u = hh - sV;
    float yi = yL[idx][o], yi1 = yL[idx+1][o];
    float M0 = (idx == 0) ? 0.f : dpM[(idx-1)*128 + o];
    float M1 = (idx == 62) ? 0.f : dpM[idx*128 + o];
    float val = (M0*u*u*u + M1*sV*sV*sV)*(1.f/(6.f*hh))
              + (yi  - M0*hh6)*(u*(1.f/hh))
              + (yi1 - M1*hh6)*(sV*(1.f/hh));
    adst[(size_t)l*NN + o] = val;
  }
}

// ---------------- K_conv2g: conv2 as GEMM -> t2b[(b*16+j2)][o], K = ci*4+kk ----------------
__global__ __launch_bounds__(256) void k_conv2g(const float* __restrict__ t1tg, const float* __restrict__ w,
    const float* __restrict__ bias, float* __restrict__ t2b){
  __shared__ alignas(16) float As[16][68];
  __shared__ alignas(16) float Bs[16][68];
  int tid = threadIdx.x;
  int r0 = blockIdx.x*64, o0 = blockIdx.y*64;
  float acc[4][4] = {};
  int ar = tid & 63, ak = tid >> 6;
  int bk = tid & 15, bc = tid >> 4;
  int tr = tid & 15, tc = tid >> 4;
  int rb = (r0 + ar) >> 4, rj = (r0 + ar) & 15;
  for(int k0=0;k0<512;k0+=16){
    #pragma unroll
    for(int q=0;q<4;q++){
      int k = ak*4 + q, K = k0 + k;
      int ci = K >> 2, kk = K & 3;
      Bs[k][ar] = t1tg[((size_t)rb*64 + 4*rj + kk)*NN + ci];
    }
    #pragma unroll
    for(int q=0;q<4;q++){
      int oo = bc + 16*q;
      As[bk][oo] = w[(size_t)(o0+oo)*512 + k0 + bk];
    }
    __syncthreads();
    #pragma unroll
    for(int kk2=0;kk2<16;kk2++){
      float4 av = *(const float4*)&Bs[kk2][4*tr];
      float4 bv = *(const float4*)&As[kk2][4*tc];
      float aa[4] = {av.x, av.y, av.z, av.w};
      float bb[4] = {bv.x, bv.y, bv.z, bv.w};
      #pragma unroll
      for(int i=0;i<4;i++)
        #pragma unroll
        for(int j=0;j<4;j++) acc[i][j] = fmaf(aa[i], bb[j], acc[i][j]);
    }
    __syncthreads();
  }
  #pragma unroll
  for(int i=0;i<4;i++){
    int r = r0 + 4*tr + i;
    int o = o0 + 4*tc;
    float4 st;
    st.x = acc[i][0] + bias[o+0];
    st.y = acc[i][1] + bias[o+1];
    st.z = acc[i][2] + bias[o+2];
    st.w = acc[i][3] + bias[o+3];
    *(float4*)&t2b[(size_t)r*NN + o] = st;
  }
}

// ---------------- K_mid4: BN2 + ELU + spline solve16 + eval16 (block per b) ----------------
__global__ __launch_bounds__(256) void k_mid4(const float* __restrict__ t2b, const float* __restrict__ g,
    const float* __restrict__ bb, float* __restrict__ a){
  __shared__ float yL[16][128];
  __shared__ float dpM[14*128];
  __shared__ float cp[14];
  int b = blockIdx.x, tid = threadIdx.x;
  int o = tid & 127, h = tid >> 7;
  if(tid == 0){
    float cv = 0.25f; cp[0] = cv;
    for(int i=1;i<14;i++){ cv = 1.f/(4.f - cv); cp[i] = cv; }
  }
  float s = 0.f, s2 = 0.f;
  for(int r=h*128; r<h*128+128; r++){
    float v = t2b[(size_t)r*NN + o];
    s += v; s2 += v*v;
  }
  dpM[h*128 + o] = s; dpM[256 + h*128 + o] = s2;
  __syncthreads();
  float stot = dpM[o] + dpM[128+o], s2tot = dpM[256+o] + dpM[384+o];
  float mu = stot*(1.f/256.f);
  float var = fmaxf(s2tot*(1.f/256.f) - mu*mu, 0.f);
  float sc = g[o]*rsqrtf(var + EPSF);
  float sh = bb[o] - mu*sc;
  __syncthreads();
  for(int j=h*8; j<h*8+8; j++){
    float v = t2b[((size_t)b*16 + j)*NN + o]*sc + sh;
    v = v > 0.f ? v : (expf(v) - 1.f);
    yL[j][o] = v;
  }
  __syncthreads();
  if(h == 0){
    const float Kc = 6.f*15.f*15.f;
    float y0 = yL[0][o], y1 = yL[1][o], dprev = 0.f;
    for(int i=0;i<14;i++){
      float y2 = yL[i+2][o];
      float r = (y2 - 2.f*y1 + y0)*Kc;
      float d = (i == 0) ? r*0.25f : (r - dprev)*cp[i];
      dpM[i*128 + o] = d; dprev = d;
      y0 = y1; y1 = y2;
    }
    float xv = dpM[13*128 + o];
    for(int i=12;i>=0;i--){
      xv = dpM[i*128 + o] - cp[i]*xv;
      dpM[i*128 + o] = xv;
    }
  }
  __syncthreads();
  const float hh = 1.f/15.f, hh6 = hh*hh/6.f;
  float* adst = a + ((size_t)b*3 + 2)*LL*NN;
  for(int l=h*384; l<h*384+384; l++){
    float q = (float)l*(1.f/767.f);
    int idx = (int)floorf(q*15.f); if(idx > 14) idx = 14;
    float sV = q - idx*hh, u = hh - sV;
    float yi = yL[idx][o], yi1 = yL[idx+1][o];
    float M0 = (idx == 0) ? 0.f : dpM[(idx-1)*128 + o];
    float M1 = (idx == 14) ? 0.f : dpM[idx*128 + o];
    float val = (M0*u*u*u + M1*sV*sV*sV)*(1.f/(6.f*hh))
              + (yi  - M0*hh6)*(u*(1.f/hh))
              + (yi1 - M1*hh6)*(sV*(1.f/hh));
    adst[(size_t)l*NN + o] = val;
  }
}

// ---------------- K13: fused conv2d stage -> co_t[b,l,n] = h2 + x^T (unchanged) ----------------
__global__ __launch_bounds__(256) void k_fusedconv(const float* __restrict__ a,
    const float* __restrict__ w0, const float* __restrict__ b0,
    const float* __restrict__ w1, const float* __restrict__ b1,
    const float* __restrict__ vwsT, const float* __restrict__ vb0,
    const float* __restrict__ vb1, float* __restrict__ cot){
  constexpr int TL = 8, TN = 32;
  constexpr int AY = TL+4, AX = 40;
  constexpr int HY = TL+2, HX = TN+2;
  constexpr int CP = 34;
  __shared__ alignas(16) float as[3][AY][AX];
  __shared__ alignas(16) float h1s[HY][HX][CP];
  int tid = threadIdx.x;
  int l0 = blockIdx.x*TL, n0 = blockIdx.y*TN, b = blockIdx.z;

  const float* ab = a + (size_t)b*3*LL*NN;
  float* asf = &as[0][0][0];
  for(int i=tid;i<3*AY*AX;i+=256){
    int ch = i/(AY*AX), rem = i%(AY*AX), yy = rem/AX, xx = rem%AX;
    int gl = l0 + yy - 2, gn = n0 + xx - 2;
    float v = 0.f;
    if(gl >= 0 && gl < LL && gn >= 0 && gn < NN) v = ab[((size_t)ch*LL + gl)*NN + gn];
    asf[i] = v;
  }

  int c = tid & 31, qg = tid >> 5;
  float wr[3][3][3];
  #pragma unroll
  for(int ci=0;ci<3;ci++)
    #pragma unroll
    for(int dy=0;dy<3;dy++)
      #pragma unroll
      for(int dx=0;dx<3;dx++){
        float wv = 0.5f*w1[((c*3+ci)*3+dy)*3+dx];
        if(dy==1 && dx==1) wv += 0.5f*w0[c*3+ci];
        wr[ci][dy][dx] = wv;
      }
  float br = 0.5f*(b0[c] + b1[c]);
  __syncthreads();

  for(int q=qg; q<90; q+=8){
    int yy = q/9, x0 = (q%9)*4;
    float win[3][3][6];
    #pragma unroll
    for(int ci=0;ci<3;ci++)
      #pragma unroll
      for(int dy=0;dy<3;dy++){
        float4 r4 = *(const float4*)&as[ci][yy+dy][x0];
        float2 r2 = *(const float2*)&as[ci][yy+dy][x0+4];
        win[ci][dy][0]=r4.x; win[ci][dy][1]=r4.y; win[ci][dy][2]=r4.z;
        win[ci][dy][3]=r4.w; win[ci][dy][4]=r2.x; win[ci][dy][5]=r2.y;
      }
    #pragma unroll
    for(int p=0;p<4;p++){
      int xx = x0 + p;
      if(xx >= HX) continue;
      int gl = l0 + yy - 1, gn = n0 + xx - 1;
      float val = 0.f;
      if(gl >= 0 && gl < LL && gn >= 0 && gn < NN){
        float s = br;
        #pragma unroll
        for(int ci=0;ci<3;ci++)
          #pragma unroll
          for(int dy=0;dy<3;dy++)
            #pragma unroll
            for(int dx=0;dx<3;dx++)
              s = fmaf(wr[ci][dy][dx], win[ci][dy][p+dx], s);
        val = s*0.5f*(1.f + erff(s*0.70710678118654752f));
      }
      h1s[yy][xx][c] = val;
    }
  }
  __syncthreads();

  int oy = tid >> 5, ox = tid & 31;
  float acc = 0.f;
  #pragma unroll
  for(int dy=0;dy<3;dy++)
    #pragma unroll
    for(int dx=0;dx<3;dx++){
      const float* hh = &h1s[oy+dy][ox+dx][0];
      const float* wt = vwsT + (dy*3+dx)*DMC;
      #pragma unroll
      for(int cg=0;cg<8;cg++){
        float2 h01 = *(const float2*)&hh[cg*4];
        float2 h23 = *(const float2*)&hh[cg*4+2];
        float4 wv = *(const float4*)&wt[cg*4];
        acc = fmaf(h01.x, wv.x, acc);
        acc = fmaf(h01.y, wv.y, acc);
        acc = fmaf(h23.x, wv.z, acc);
        acc = fmaf(h23.y, wv.w, acc);
      }
    }
  float resid = as[0][oy+2][ox+2];
  cot[((size_t)b*LL + l0 + oy)*NN + n0 + ox] = acc + vb0[0] + vb1[0] + resid;
}

// ---------------- K15: tiled GEMM2 + de-normalize (stats from partials) ----------------
__global__ __launch_bounds__(256) void k_gemm2(const float* __restrict__ cot, const float* __restrict__ ldw,
    const float* __restrict__ ldb, const float* __restrict__ sp, const float* __restrict__ s2p,
    float* __restrict__ out){
  __shared__ alignas(16) float As[16][68];
  __shared__ alignas(16) float Bs[16][68];
  int tid = threadIdx.x;
  int row0 = blockIdx.x*64, p0 = blockIdx.y*64;
  int b = row0 >> 7, n0 = row0 & 127;
  float acc[4][4] = {};
  int ar = tid & 63, ak = tid >> 6;
  int lk = tid & 15, lr = tid >> 4;
  int tr = tid & 15, tc = tid >> 4;
  for(int k0=0;k0<LL;k0+=16){
    #pragma unroll
    for(int q=0;q<4;q++){
      int k = ak*4 + q;
      As[k][ar] = cot[((size_t)b*LL + k0 + k)*NN + n0 + ar];
    }
    #pragma unroll
    for(int q=0;q<4;q++){
      int cc = lr + 16*q;
      Bs[lk][cc] = ldw[(size_t)(p0+cc)*LL + k0 + lk];
    }
    __syncthreads();
    #pragma unroll
    for(int kk=0;kk<16;kk++){
      float4 av = *(const float4*)&As[kk][4*tr];
      float4 bv = *(const float4*)&Bs[kk][4*tc];
      float aa[4] = {av.x, av.y, av.z, av.w};
      float bb[4] = {bv.x, bv.y, bv.z, bv.w};
      #pragma unroll
      for(int i=0;i<4;i++)
        #pragma unroll
        for(int j=0;j<4;j++) acc[i][j] = fmaf(aa[i], bb[j], acc[i][j]);
    }
    __syncthreads();
  }
  #pragma unroll
  for(int i=0;i<4;i++){
    int row = row0 + 4*tr + i;
    int bb2 = row >> 7, n = row & 127;
    float ssum = 0.f, s2sum = 0.f;
    #pragma unroll
    for(int tq=0;tq<4;tq++){ ssum += sp[tq*2048 + row]; s2sum += s2p[tq*2048 + row]; }
    float mu = ssum*(1.f/512.f);
    float var = fmaxf(s2sum*(1.f/512.f) - mu*mu, 0.f);
    float sd = sqrtf(var + EPSF);
    #pragma unroll
    for(int j=0;j<4;j++){
      int p = p0 + 4*tc + j;
      float v = (acc[i][j] + ldb[p])*sd + mu;
      out[((size_t)bb2*PREDN + p)*NN + n] = v;
    }
  }
}

extern "C" void kernel_launch(void* const* d_in, const int* in_sizes, int n_in,
                              void* d_out, int out_size, void* d_ws, size_t ws_size,
                              hipStream_t stream){
  (void)in_sizes; (void)n_in; (void)out_size; (void)ws_size;
  const float* batch_x = (const float*)d_in[0];
  const float* le_w  = (const float*)d_in[4];
  const float* le_b  = (const float*)d_in[5];
  const float* c1_w  = (const float*)d_in[6];
  const float* c1_b  = (const float*)d_in[7];
  const float* bn1_g = (const float*)d_in[8];
  const float* bn1_b = (const float*)d_in[9];
  const float* c2_w  = (const float*)d_in[10];
  const float* c2_b  = (const float*)d_in[11];
  const float* bn2_g = (const float*)d_in[12];
  const float* bn2_b = (const float*)d_in[13];
  const float* i1_w0 = (const float*)d_in[14];
  const float* i1_b0 = (const float*)d_in[15];
  const float* i1_w1 = (const float*)d_in[16];
  const float* i1_b1 = (const float*)d_in[17];
  const float* i2_w0 = (const float*)d_in[18];
  const float* i2_b0 = (const float*)d_in[19];
  const float* i2_w1 = (const float*)d_in[20];
  const float* i2_b1 = (const float*)d_in[21];
  const float* ld_w  = (const float*)d_in[22];
  const float* ld_b  = (const float*)d_in[23];
  float* out = (float*)d_out;

  float* ws   = (float*)d_ws;
  float* sp   = ws;                       // 4*2048
  float* s2p  = sp + 8192;                // 4*2048
  float* vwsT = s2p + 8192;               // 288 (+pad)
  float* x    = vwsT + 320;               // 16*128*768
  float* a    = x + (size_t)BB*NN*LL;     // 16*3*768*128
  float* t1b  = a + (size_t)BB*3*LL*NN;   // 16*64*128
  float* t1tg = t1b + (size_t)BB*64*NN;   // 16*64*128
  float* t2b  = t1tg + (size_t)BB*64*NN;  // 16*16*128
  float* cot  = t2b + (size_t)BB*16*NN;   // 16*768*128
  float* a0   = a;

  k_pre<<<65, 128, 0, stream>>>(batch_x, i2_w0, i2_w1, sp, s2p, vwsT);
  k_gemm1<<<dim3(32,12), 256, 0, stream>>>(batch_x, le_w, le_b, sp, s2p, x, a0);
  k_conv1g<<<dim3(16,2), 256, 0, stream>>>(x, c1_w, c1_b, t1b);
  k_mid2<<<16, 256, 0, stream>>>(t1b, bn1_g, bn1_b, t1tg, a);
  k_conv2g<<<dim3(4,2), 256, 0, stream>>>(t1tg, c2_w, c2_b, t2b);
  k_mid4<<<16, 256, 0, stream>>>(t2b, bn2_g, bn2_b, a);
  k_fusedconv<<<dim3(LL/8, NN/32, BB), 256, 0, stream>>>(a, i1_w0, i1_b0, i1_w1, i1_b1,
                                                         vwsT, i2_b0, i2_b1, cot);
  k_gemm2<<<dim3(32,4), 256, 0, stream>>>(cot, ld_w, ld_b, sp, s2p, out);
}

// Round 9
// 448.670 us; speedup vs baseline: 1.3698x; 1.3698x over previous
//
#include <hip/hip_runtime.h>
#include <hip/hip_bf16.h>
#include <math.h>

#define BB 16
#define TT 512
#define NN 128
#define PREDN 256
#define DMC 32
#define LL 768
constexpr float EPSF = 1e-5f;

// ---------------- K_pre: blocks 0..63 = partial stats over t-quarters; block 64 = weight fold ----------------
__global__ void k_pre(const float* __restrict__ bx, const float* __restrict__ v0,
                      const float* __restrict__ v1, float* __restrict__ sp,
                      float* __restrict__ s2p, float* __restrict__ vwsT){
  int blk = blockIdx.x;
  if(blk == 64){
    for(int i=threadIdx.x; i<9*DMC; i+=blockDim.x){
      int tap = i/DMC, c = i%DMC;
      float wv = 0.5f*v1[c*9 + tap];
      if(tap == 4) wv += 0.5f*v0[c];
      vwsT[i] = wv;
    }
    return;
  }
  int b = blk >> 2, tq = blk & 3, n = threadIdx.x;
  const float* p = bx + (size_t)b*TT*NN + (size_t)tq*128*NN + n;
  float s = 0.f, s2 = 0.f;
  for(int t=0;t<128;t++){ float v = p[(size_t)t*NN]; s += v; s2 += v*v; }
  sp[tq*2048 + b*NN + n] = s;
  s2p[tq*2048 + b*NN + n] = s2;
}

// ---------------- K1: tiled GEMM1 with fused normalization + dual store ----------------
__global__ __launch_bounds__(256) void k_gemm1(const float* __restrict__ bx, const float* __restrict__ lew,
    const float* __restrict__ leb, const float* __restrict__ sp, const float* __restrict__ s2p,
    float* __restrict__ x, float* __restrict__ a0){
  __shared__ alignas(16) float As[16][68];
  __shared__ alignas(16) float Bs[16][68];
  int tid = threadIdx.x;
  int row0 = blockIdx.x*64, l0 = blockIdx.y*64;
  int b = row0 >> 7, n0 = row0 & 127;
  float acc[4][4] = {};
  int ar = tid & 63, ak = tid >> 6;
  int bk = tid & 15, bc = tid >> 4;
  int tr = tid & 15, tc = tid >> 4;
  int rowa = row0 + ar;
  float ssum = 0.f, s2sum = 0.f;
  #pragma unroll
  for(int tq=0;tq<4;tq++){ ssum += sp[tq*2048 + rowa]; s2sum += s2p[tq*2048 + rowa]; }
  float mu_a = ssum*(1.f/512.f);
  float rs_a = 1.f/sqrtf(fmaxf(s2sum*(1.f/512.f) - mu_a*mu_a, 0.f) + EPSF);
  for(int k0=0;k0<TT;k0+=16){
    #pragma unroll
    for(int q=0;q<4;q++){
      int k = ak*4 + q;
      As[k][ar] = (bx[((size_t)b*TT + k0 + k)*NN + n0 + ar] - mu_a)*rs_a;
    }
    #pragma unroll
    for(int q=0;q<4;q++){
      int c = bc + 16*q;
      Bs[bk][c] = lew[(size_t)(l0+c)*TT + k0 + bk];
    }
    __syncthreads();
    #pragma unroll
    for(int kk=0;kk<16;kk++){
      float4 av = *(const float4*)&As[kk][4*tr];
      float4 bv = *(const float4*)&Bs[kk][4*tc];
      float aa[4] = {av.x, av.y, av.z, av.w};
      float bb[4] = {bv.x, bv.y, bv.z, bv.w};
      #pragma unroll
      for(int i=0;i<4;i++)
        #pragma unroll
        for(int j=0;j<4;j++) acc[i][j] = fmaf(aa[i], bb[j], acc[i][j]);
    }
    __syncthreads();
  }
  #pragma unroll
  for(int i=0;i<4;i++){
    int row = row0 + 4*tr + i;
    int l = l0 + 4*tc;
    float4 st;
    st.x = acc[i][0] + leb[l+0];
    st.y = acc[i][1] + leb[l+1];
    st.z = acc[i][2] + leb[l+2];
    st.w = acc[i][3] + leb[l+3];
    *(float4*)&x[(size_t)row*LL + l] = st;
  }
  #pragma unroll
  for(int j=0;j<4;j++){
    int l = l0 + 4*tc + j;
    float lb = leb[l];
    float4 st;
    st.x = acc[0][j] + lb;
    st.y = acc[1][j] + lb;
    st.z = acc[2][j] + lb;
    st.w = acc[3][j] + lb;
    *(float4*)&a0[((size_t)b*3*LL + l)*NN + n0 + 4*tr] = st;
  }
}

// ---------------- K3: conv1d stride 12, kernel 12 (R7 version) ----------------
__global__ __launch_bounds__(128) void k_conv1(const float* __restrict__ x, const float* __restrict__ w,
                                               const float* __restrict__ bias, float* __restrict__ t1){
  __shared__ float xs[NN*12];
  int j = blockIdx.x, b = blockIdx.y, o = threadIdx.x;
  for(int i=o;i<NN*12;i+=NN){
    int ci = i/12, k = i%12;
    xs[i] = x[((size_t)b*NN + ci)*LL + j*12 + k];
  }
  __syncthreads();
  float a0 = bias[o], a1 = 0.f, a2 = 0.f, a3 = 0.f;
  const float* wp = w + (size_t)o*NN*12;
  #pragma unroll 4
  for(int i=0;i<NN*12;i+=4){
    a0 = fmaf(xs[i+0], wp[i+0], a0);
    a1 = fmaf(xs[i+1], wp[i+1], a1);
    a2 = fmaf(xs[i+2], wp[i+2], a2);
    a3 = fmaf(xs[i+3], wp[i+3], a3);
  }
  t1[((size_t)b*NN + o)*64 + j] = (a0 + a1) + (a2 + a3);
}

// ---------------- K4: BN stats per channel (R7) ----------------
__global__ void k_bnstats(const float* __restrict__ t, const float* __restrict__ g, const float* __restrict__ bb,
                          int Bcnt, int Jcnt, float* __restrict__ scale, float* __restrict__ shift){
  int o = blockIdx.x;
  int tot = Bcnt*Jcnt;
  float s = 0.f, s2 = 0.f;
  for(int i=threadIdx.x; i<tot; i+=blockDim.x){
    int b = i / Jcnt, j = i % Jcnt;
    float v = t[((size_t)b*NN + o)*Jcnt + j];
    s += v; s2 += v*v;
  }
  __shared__ float rs[256], rs2[256];
  rs[threadIdx.x] = s; rs2[threadIdx.x] = s2;
  __syncthreads();
  for(int st=128; st>0; st>>=1){
    if(threadIdx.x < st){ rs[threadIdx.x] += rs[threadIdx.x+st]; rs2[threadIdx.x] += rs2[threadIdx.x+st]; }
    __syncthreads();
  }
  if(threadIdx.x == 0){
    float mu = rs[0]/tot;
    float var = fmaxf(rs2[0]/tot - mu*mu, 0.f);
    float sc = g[o] * rsqrtf(var + EPSF);
    scale[o] = sc; shift[o] = bb[o] - mu*sc;
  }
}

// ---------------- K5: BN apply + ELU + transpose (R7) ----------------
__global__ void k_bnelu_t(const float* __restrict__ t, const float* __restrict__ scale,
                          const float* __restrict__ shift, int Jcnt, float* __restrict__ tt){
  int j = blockIdx.x, b = blockIdx.y, o = threadIdx.x;
  float v = t[((size_t)b*NN + o)*Jcnt + j]*scale[o] + shift[o];
  v = v > 0.f ? v : (expf(v) - 1.f);
  tt[((size_t)b*Jcnt + j)*NN + o] = v;
}

// ---------------- K6: spline tridiagonal solve (Thomas, R7) ----------------
template<int LK>
__global__ void k_spline_solve(const float* __restrict__ y, float* __restrict__ M){
  constexpr int m = LK-2;
  const float Kc = 6.f*(LK-1)*(LK-1);
  __shared__ float cp[m];
  __shared__ float dp[m][NN];
  int b = blockIdx.x, c = threadIdx.x;
  if(c == 0){
    float cv = 0.25f; cp[0] = cv;
    for(int i=1;i<m;i++){ cv = 1.f/(4.f - cv); cp[i] = cv; }
  }
  __syncthreads();
  const float* yb = y + (size_t)b*LK*NN + c;
  float y0 = yb[0], y1 = yb[NN];
  float dprev = 0.f;
  for(int i=0;i<m;i++){
    float y2 = yb[(size_t)(i+2)*NN];
    float r = (y2 - 2.f*y1 + y0)*Kc;
    float d = (i == 0) ? r*0.25f : (r - dprev)*cp[i];
    dp[i][c] = d; dprev = d;
    y0 = y1; y1 = y2;
  }
  float* Mb = M + (size_t)b*LK*NN + c;
  float xv = dp[m-1][c];
  Mb[(size_t)m*NN] = xv;
  for(int i=m-2;i>=0;i--){
    xv = dp[i][c] - cp[i]*xv;
    Mb[(size_t)(i+1)*NN] = xv;
  }
  Mb[0] = 0.f;
  Mb[(size_t)(LK-1)*NN] = 0.f;
}

// ---------------- K7: merged spline evaluation (both scales, z = 0/1) ----------------
__device__ __forceinline__ float spline_pt(const float* __restrict__ y, const float* __restrict__ M,
                                           int LK, int l, int b, int c){
  float hh = 1.f/(LK-1);
  float q = (float)l * (1.f/(LL-1));
  int idx = (int)floorf(q*(LK-1));
  if(idx > LK-2) idx = LK-2;
  float s = q - idx*hh;
  float u = hh - s;
  const float* yb = y + ((size_t)b*LK + idx)*NN + c;
  const float* Mb = M + ((size_t)b*LK + idx)*NN + c;
  float yi = yb[0], yi1 = yb[NN], M0 = Mb[0], M1 = Mb[NN];
  float hh6 = hh*hh/6.f;
  return (M0*u*u*u + M1*s*s*s)*(1.f/(6.f*hh))
       + (yi  - M0*hh6)*(u*(1.f/hh))
       + (yi1 - M1*hh6)*(s*(1.f/hh));
}

__global__ void k_spline_eval2(const float* __restrict__ y64, const float* __restrict__ M64,
                               const float* __restrict__ y16, const float* __restrict__ M16,
                               float* __restrict__ a){
  int l = blockIdx.x, b = blockIdx.y, ch = blockIdx.z, c = threadIdx.x;
  float val = (ch == 0) ? spline_pt(y64, M64, 64, l, b, c)
                        : spline_pt(y16, M16, 16, l, b, c);
  a[(((size_t)b*3 + 1 + ch)*LL + l)*NN + c] = val;
}

// ---------------- K8: conv1d stride 4, kernel 4 (R7) ----------------
__global__ __launch_bounds__(128) void k_conv2(const float* __restrict__ tt, const float* __restrict__ w,
                                               const float* __restrict__ bias, float* __restrict__ t2){
  __shared__ float ts[4*NN];
  int j = blockIdx.x, b = blockIdx.y, o = threadIdx.x;
  for(int i=o;i<4*NN;i+=NN) ts[i] = tt[((size_t)b*64 + j*4)*NN + i];
  __syncthreads();
  float acc = bias[o];
  const float* wp = w + (size_t)o*NN*4;
  #pragma unroll 4
  for(int ci=0;ci<NN;ci++){
    acc = fmaf(ts[0*NN+ci], wp[ci*4+0], acc);
    acc = fmaf(ts[1*NN+ci], wp[ci*4+1], acc);
    acc = fmaf(ts[2*NN+ci], wp[ci*4+2], acc);
    acc = fmaf(ts[3*NN+ci], wp[ci*4+3], acc);
  }
  t2[((size_t)b*NN + o)*16 + j] = acc;
}

// ---------------- K13: fused conv2d stage -> co_t[b,l,n] = h2 + x^T (unchanged) ----------------
__global__ __launch_bounds__(256) void k_fusedconv(const float* __restrict__ a,
    const float* __restrict__ w0, const float* __restrict__ b0,
    const float* __restrict__ w1, const float* __restrict__ b1,
    const float* __restrict__ vwsT, const float* __restrict__ vb0,
    const float* __restrict__ vb1, float* __restrict__ cot){
  constexpr int TL = 8, TN = 32;
  constexpr int AY = TL+4, AX = 40;
  constexpr int HY = TL+2, HX = TN+2;
  constexpr int CP = 34;
  __shared__ alignas(16) float as[3][AY][AX];
  __shared__ alignas(16) float h1s[HY][HX][CP];
  int tid = threadIdx.x;
  int l0 = blockIdx.x*TL, n0 = blockIdx.y*TN, b = blockIdx.z;

  const float* ab = a + (size_t)b*3*LL*NN;
  float* asf = &as[0][0][0];
  for(int i=tid;i<3*AY*AX;i+=256){
    int ch = i/(AY*AX), rem = i%(AY*AX), yy = rem/AX, xx = rem%AX;
    int gl = l0 + yy - 2, gn = n0 + xx - 2;
    float v = 0.f;
    if(gl >= 0 && gl < LL && gn >= 0 && gn < NN) v = ab[((size_t)ch*LL + gl)*NN + gn];
    asf[i] = v;
  }

  int c = tid & 31, qg = tid >> 5;
  float wr[3][3][3];
  #pragma unroll
  for(int ci=0;ci<3;ci++)
    #pragma unroll
    for(int dy=0;dy<3;dy++)
      #pragma unroll
      for(int dx=0;dx<3;dx++){
        float wv = 0.5f*w1[((c*3+ci)*3+dy)*3+dx];
        if(dy==1 && dx==1) wv += 0.5f*w0[c*3+ci];
        wr[ci][dy][dx] = wv;
      }
  float br = 0.5f*(b0[c] + b1[c]);
  __syncthreads();

  for(int q=qg; q<90; q+=8){
    int yy = q/9, x0 = (q%9)*4;
    float win[3][3][6];
    #pragma unroll
    for(int ci=0;ci<3;ci++)
      #pragma unroll
      for(int dy=0;dy<3;dy++){
        float4 r4 = *(const float4*)&as[ci][yy+dy][x0];
        float2 r2 = *(const float2*)&as[ci][yy+dy][x0+4];
        win[ci][dy][0]=r4.x; win[ci][dy][1]=r4.y; win[ci][dy][2]=r4.z;
        win[ci][dy][3]=r4.w; win[ci][dy][4]=r2.x; win[ci][dy][5]=r2.y;
      }
    #pragma unroll
    for(int p=0;p<4;p++){
      int xx = x0 + p;
      if(xx >= HX) continue;
      int gl = l0 + yy - 1, gn = n0 + xx - 1;
      float val = 0.f;
      if(gl >= 0 && gl < LL && gn >= 0 && gn < NN){
        float s = br;
        #pragma unroll
        for(int ci=0;ci<3;ci++)
          #pragma unroll
          for(int dy=0;dy<3;dy++)
            #pragma unroll
            for(int dx=0;dx<3;dx++)
              s = fmaf(wr[ci][dy][dx], win[ci][dy][p+dx], s);
        val = s*0.5f*(1.f + erff(s*0.70710678118654752f));
      }
      h1s[yy][xx][c] = val;
    }
  }
  __syncthreads();

  int oy = tid >> 5, ox = tid & 31;
  float acc = 0.f;
  #pragma unroll
  for(int dy=0;dy<3;dy++)
    #pragma unroll
    for(int dx=0;dx<3;dx++){
      const float* hh = &h1s[oy+dy][ox+dx][0];
      const float* wt = vwsT + (dy*3+dx)*DMC;
      #pragma unroll
      for(int cg=0;cg<8;cg++){
        float2 h01 = *(const float2*)&hh[cg*4];
        float2 h23 = *(const float2*)&hh[cg*4+2];
        float4 wv = *(const float4*)&wt[cg*4];
        acc = fmaf(h01.x, wv.x, acc);
        acc = fmaf(h01.y, wv.y, acc);
        acc = fmaf(h23.x, wv.z, acc);
        acc = fmaf(h23.y, wv.w, acc);
      }
    }
  float resid = as[0][oy+2][ox+2];
  cot[((size_t)b*LL + l0 + oy)*NN + n0 + ox] = acc + vb0[0] + vb1[0] + resid;
}

// ---------------- K15: tiled GEMM2 + de-normalize (stats from partials) ----------------
__global__ __launch_bounds__(256) void k_gemm2(const float* __restrict__ cot, const float* __restrict__ ldw,
    const float* __restrict__ ldb, const float* __restrict__ sp, const float* __restrict__ s2p,
    float* __restrict__ out){
  __shared__ alignas(16) float As[16][68];
  __shared__ alignas(16) float Bs[16][68];
  int tid = threadIdx.x;
  int row0 = blockIdx.x*64, p0 = blockIdx.y*64;
  int b = row0 >> 7, n0 = row0 & 127;
  float acc[4][4] = {};
  int ar = tid & 63, ak = tid >> 6;
  int lk = tid & 15, lr = tid >> 4;
  int tr = tid & 15, tc = tid >> 4;
  for(int k0=0;k0<LL;k0+=16){
    #pragma unroll
    for(int q=0;q<4;q++){
      int k = ak*4 + q;
      As[k][ar] = cot[((size_t)b*LL + k0 + k)*NN + n0 + ar];
    }
    #pragma unroll
    for(int q=0;q<4;q++){
      int cc = lr + 16*q;
      Bs[lk][cc] = ldw[(size_t)(p0+cc)*LL + k0 + lk];
    }
    __syncthreads();
    #pragma unroll
    for(int kk=0;kk<16;kk++){
      float4 av = *(const float4*)&As[kk][4*tr];
      float4 bv = *(const float4*)&Bs[kk][4*tc];
      float aa[4] = {av.x, av.y, av.z, av.w};
      float bb[4] = {bv.x, bv.y, bv.z, bv.w};
      #pragma unroll
      for(int i=0;i<4;i++)
        #pragma unroll
        for(int j=0;j<4;j++) acc[i][j] = fmaf(aa[i], bb[j], acc[i][j]);
    }
    __syncthreads();
  }
  #pragma unroll
  for(int i=0;i<4;i++){
    int row = row0 + 4*tr + i;
    int bb2 = row >> 7, n = row & 127;
    float ssum = 0.f, s2sum = 0.f;
    #pragma unroll
    for(int tq=0;tq<4;tq++){ ssum += sp[tq*2048 + row]; s2sum += s2p[tq*2048 + row]; }
    float mu = ssum*(1.f/512.f);
    float var = fmaxf(s2sum*(1.f/512.f) - mu*mu, 0.f);
    float sd = sqrtf(var + EPSF);
    #pragma unroll
    for(int j=0;j<4;j++){
      int p = p0 + 4*tc + j;
      float v = (acc[i][j] + ldb[p])*sd + mu;
      out[((size_t)bb2*PREDN + p)*NN + n] = v;
    }
  }
}

extern "C" void kernel_launch(void* const* d_in, const int* in_sizes, int n_in,
                              void* d_out, int out_size, void* d_ws, size_t ws_size,
                              hipStream_t stream){
  (void)in_sizes; (void)n_in; (void)out_size; (void)ws_size;
  const float* batch_x = (const float*)d_in[0];
  const float* le_w  = (const float*)d_in[4];
  const float* le_b  = (const float*)d_in[5];
  const float* c1_w  = (const float*)d_in[6];
  const float* c1_b  = (const float*)d_in[7];
  const float* bn1_g = (const float*)d_in[8];
  const float* bn1_b = (const float*)d_in[9];
  const float* c2_w  = (const float*)d_in[10];
  const float* c2_b  = (const float*)d_in[11];
  const float* bn2_g = (const float*)d_in[12];
  const float* bn2_b = (const float*)d_in[13];
  const float* i1_w0 = (const float*)d_in[14];
  const float* i1_b0 = (const float*)d_in[15];
  const float* i1_w1 = (const float*)d_in[16];
  const float* i1_b1 = (const float*)d_in[17];
  const float* i2_w0 = (const float*)d_in[18];
  const float* i2_b0 = (const float*)d_in[19];
  const float* i2_w1 = (const float*)d_in[20];
  const float* i2_b1 = (const float*)d_in[21];
  const float* ld_w  = (const float*)d_in[22];
  const float* ld_b  = (const float*)d_in[23];
  float* out = (float*)d_out;

  float* ws   = (float*)d_ws;
  float* sp   = ws;                       // 8192
  float* s2p  = sp + 8192;                // 8192
  float* vwsT = s2p + 8192;               // 288 (+pad)
  float* x    = vwsT + 320;               // 16*128*768
  float* a    = x + (size_t)BB*NN*LL;     // 16*3*768*128
  float* t1   = a + (size_t)BB*3*LL*NN;   // 131,072
  float* t1t  = t1 + (size_t)BB*NN*64;    // 131,072
  float* sc1  = t1t + (size_t)BB*64*NN;   // 128
  float* sh1  = sc1 + NN;                 // 128
  float* Msp1 = sh1 + NN;                 // 131,072
  float* t2   = Msp1 + (size_t)BB*64*NN;  // 32,768
  float* t2t  = t2 + (size_t)BB*NN*16;    // 32,768
  float* sc2  = t2t + (size_t)BB*16*NN;   // 128
  float* sh2  = sc2 + NN;                 // 128
  float* Msp2 = sh2 + NN;                 // 32,768
  float* cot  = Msp2 + (size_t)BB*16*NN;  // 16*768*128
  float* a0   = a;

  k_pre<<<65, 128, 0, stream>>>(batch_x, i2_w0, i2_w1, sp, s2p, vwsT);
  k_gemm1<<<dim3(32,12), 256, 0, stream>>>(batch_x, le_w, le_b, sp, s2p, x, a0);
  k_conv1<<<dim3(64,BB), NN, 0, stream>>>(x, c1_w, c1_b, t1);
  k_bnstats<<<NN, 256, 0, stream>>>(t1, bn1_g, bn1_b, BB, 64, sc1, sh1);
  k_bnelu_t<<<dim3(64,BB), NN, 0, stream>>>(t1, sc1, sh1, 64, t1t);
  k_spline_solve<64><<<BB, NN, 0, stream>>>(t1t, Msp1);
  k_conv2<<<dim3(16,BB), NN, 0, stream>>>(t1t, c2_w, c2_b, t2);
  k_bnstats<<<NN, 256, 0, stream>>>(t2, bn2_g, bn2_b, BB, 16, sc2, sh2);
  k_bnelu_t<<<dim3(16,BB), NN, 0, stream>>>(t2, sc2, sh2, 16, t2t);
  k_spline_solve<16><<<BB, NN, 0, stream>>>(t2t, Msp2);
  k_spline_eval2<<<dim3(LL,BB,2), NN, 0, stream>>>(t1t, Msp1, t2t, Msp2, a);
  k_fusedconv<<<dim3(LL/8, NN/32, BB), 256, 0, stream>>>(a, i1_w0, i1_b0, i1_w1, i1_b1,
                                                         vwsT, i2_b0, i2_b1, cot);
  k_gemm2<<<dim3(32,4), 256, 0, stream>>>(cot, ld_w, ld_b, sp, s2p, out);
}

// Round 10
// 447.402 us; speedup vs baseline: 1.3737x; 1.0028x over previous
//
#include <hip/hip_runtime.h>
#include <hip/hip_bf16.h>
#include <math.h>

#define BB 16
#define TT 512
#define NN 128
#define PREDN 256
#define DMC 32
#define LL 768
constexpr float EPSF = 1e-5f;
using bf16 = __hip_bfloat16;

// ---------------- K_pre: blocks 0..63 = partial stats; block 64 = stage-2 weight fold ----------------
__global__ void k_pre(const float* __restrict__ bx, const float* __restrict__ v0,
                      const float* __restrict__ v1, float* __restrict__ sp,
                      float* __restrict__ s2p, float* __restrict__ vwsT){
  int blk = blockIdx.x;
  if(blk == 64){
    for(int i=threadIdx.x; i<9*DMC; i+=blockDim.x){
      int tap = i/DMC, c = i%DMC;
      float wv = 0.5f*v1[c*9 + tap];
      if(tap == 4) wv += 0.5f*v0[c];
      vwsT[i] = wv;
    }
    return;
  }
  int b = blk >> 2, tq = blk & 3, n = threadIdx.x;
  const float* p = bx + (size_t)b*TT*NN + (size_t)tq*128*NN + n;
  float s = 0.f, s2 = 0.f;
  for(int t=0;t<128;t++){ float v = p[(size_t)t*NN]; s += v; s2 += v*v; }
  sp[tq*2048 + b*NN + n] = s;
  s2p[tq*2048 + b*NN + n] = s2;
}

// ---------------- K1: tiled GEMM1 with fused normalization + dual store ----------------
__global__ __launch_bounds__(256) void k_gemm1(const float* __restrict__ bx, const float* __restrict__ lew,
    const float* __restrict__ leb, const float* __restrict__ sp, const float* __restrict__ s2p,
    float* __restrict__ x, float* __restrict__ a0){
  __shared__ alignas(16) float As[16][68];
  __shared__ alignas(16) float Bs[16][68];
  int tid = threadIdx.x;
  int row0 = blockIdx.x*64, l0 = blockIdx.y*64;
  int b = row0 >> 7, n0 = row0 & 127;
  float acc[4][4] = {};
  int ar = tid & 63, ak = tid >> 6;
  int bk = tid & 15, bc = tid >> 4;
  int tr = tid & 15, tc = tid >> 4;
  int rowa = row0 + ar;
  float ssum = 0.f, s2sum = 0.f;
  #pragma unroll
  for(int tq=0;tq<4;tq++){ ssum += sp[tq*2048 + rowa]; s2sum += s2p[tq*2048 + rowa]; }
  float mu_a = ssum*(1.f/512.f);
  float rs_a = 1.f/sqrtf(fmaxf(s2sum*(1.f/512.f) - mu_a*mu_a, 0.f) + EPSF);
  for(int k0=0;k0<TT;k0+=16){
    #pragma unroll
    for(int q=0;q<4;q++){
      int k = ak*4 + q;
      As[k][ar] = (bx[((size_t)b*TT + k0 + k)*NN + n0 + ar] - mu_a)*rs_a;
    }
    #pragma unroll
    for(int q=0;q<4;q++){
      int c = bc + 16*q;
      Bs[bk][c] = lew[(size_t)(l0+c)*TT + k0 + bk];
    }
    __syncthreads();
    #pragma unroll
    for(int kk=0;kk<16;kk++){
      float4 av = *(const float4*)&As[kk][4*tr];
      float4 bv = *(const float4*)&Bs[kk][4*tc];
      float aa[4] = {av.x, av.y, av.z, av.w};
      float bb[4] = {bv.x, bv.y, bv.z, bv.w};
      #pragma unroll
      for(int i=0;i<4;i++)
        #pragma unroll
        for(int j=0;j<4;j++) acc[i][j] = fmaf(aa[i], bb[j], acc[i][j]);
    }
    __syncthreads();
  }
  #pragma unroll
  for(int i=0;i<4;i++){
    int row = row0 + 4*tr + i;
    int l = l0 + 4*tc;
    float4 st;
    st.x = acc[i][0] + leb[l+0];
    st.y = acc[i][1] + leb[l+1];
    st.z = acc[i][2] + leb[l+2];
    st.w = acc[i][3] + leb[l+3];
    *(float4*)&x[(size_t)row*LL + l] = st;
  }
  #pragma unroll
  for(int j=0;j<4;j++){
    int l = l0 + 4*tc + j;
    float lb = leb[l];
    float4 st;
    st.x = acc[0][j] + lb;
    st.y = acc[1][j] + lb;
    st.z = acc[2][j] + lb;
    st.w = acc[3][j] + lb;
    *(float4*)&a0[((size_t)b*3*LL + l)*NN + n0 + 4*tr] = st;
  }
}

// ---------------- K3: conv1d stride 12, kernel 12 ----------------
__global__ __launch_bounds__(128) void k_conv1(const float* __restrict__ x, const float* __restrict__ w,
                                               const float* __restrict__ bias, float* __restrict__ t1){
  __shared__ float xs[NN*12];
  int j = blockIdx.x, b = blockIdx.y, o = threadIdx.x;
  for(int i=o;i<NN*12;i+=NN){
    int ci = i/12, k = i%12;
    xs[i] = x[((size_t)b*NN + ci)*LL + j*12 + k];
  }
  __syncthreads();
  float a0 = bias[o], a1 = 0.f, a2 = 0.f, a3 = 0.f;
  const float* wp = w + (size_t)o*NN*12;
  #pragma unroll 4
  for(int i=0;i<NN*12;i+=4){
    a0 = fmaf(xs[i+0], wp[i+0], a0);
    a1 = fmaf(xs[i+1], wp[i+1], a1);
    a2 = fmaf(xs[i+2], wp[i+2], a2);
    a3 = fmaf(xs[i+3], wp[i+3], a3);
  }
  t1[((size_t)b*NN + o)*64 + j] = (a0 + a1) + (a2 + a3);
}

// ---------------- K4: BN stats per channel ----------------
__global__ void k_bnstats(const float* __restrict__ t, const float* __restrict__ g, const float* __restrict__ bb,
                          int Bcnt, int Jcnt, float* __restrict__ scale, float* __restrict__ shift){
  int o = blockIdx.x;
  int tot = Bcnt*Jcnt;
  float s = 0.f, s2 = 0.f;
  for(int i=threadIdx.x; i<tot; i+=blockDim.x){
    int b = i / Jcnt, j = i % Jcnt;
    float v = t[((size_t)b*NN + o)*Jcnt + j];
    s += v; s2 += v*v;
  }
  __shared__ float rs[256], rs2[256];
  rs[threadIdx.x] = s; rs2[threadIdx.x] = s2;
  __syncthreads();
  for(int st=128; st>0; st>>=1){
    if(threadIdx.x < st){ rs[threadIdx.x] += rs[threadIdx.x+st]; rs2[threadIdx.x] += rs2[threadIdx.x+st]; }
    __syncthreads();
  }
  if(threadIdx.x == 0){
    float mu = rs[0]/tot;
    float var = fmaxf(rs2[0]/tot - mu*mu, 0.f);
    float sc = g[o] * rsqrtf(var + EPSF);
    scale[o] = sc; shift[o] = bb[o] - mu*sc;
  }
}

// ---------------- K5: BN apply + ELU + transpose ----------------
__global__ void k_bnelu_t(const float* __restrict__ t, const float* __restrict__ scale,
                          const float* __restrict__ shift, int Jcnt, float* __restrict__ tt){
  int j = blockIdx.x, b = blockIdx.y, o = threadIdx.x;
  float v = t[((size_t)b*NN + o)*Jcnt + j]*scale[o] + shift[o];
  v = v > 0.f ? v : (expf(v) - 1.f);
  tt[((size_t)b*Jcnt + j)*NN + o] = v;
}

// ---------------- K6: spline tridiagonal solve (Thomas) ----------------
template<int LK>
__global__ void k_spline_solve(const float* __restrict__ y, float* __restrict__ M){
  constexpr int m = LK-2;
  const float Kc = 6.f*(LK-1)*(LK-1);
  __shared__ float cp[m];
  __shared__ float dp[m][NN];
  int b = blockIdx.x, c = threadIdx.x;
  if(c == 0){
    float cv = 0.25f; cp[0] = cv;
    for(int i=1;i<m;i++){ cv = 1.f/(4.f - cv); cp[i] = cv; }
  }
  __syncthreads();
  const float* yb = y + (size_t)b*LK*NN + c;
  float y0 = yb[0], y1 = yb[NN];
  float dprev = 0.f;
  for(int i=0;i<m;i++){
    float y2 = yb[(size_t)(i+2)*NN];
    float r = (y2 - 2.f*y1 + y0)*Kc;
    float d = (i == 0) ? r*0.25f : (r - dprev)*cp[i];
    dp[i][c] = d; dprev = d;
    y0 = y1; y1 = y2;
  }
  float* Mb = M + (size_t)b*LK*NN + c;
  float xv = dp[m-1][c];
  Mb[(size_t)m*NN] = xv;
  for(int i=m-2;i>=0;i--){
    xv = dp[i][c] - cp[i]*xv;
    Mb[(size_t)(i+1)*NN] = xv;
  }
  Mb[0] = 0.f;
  Mb[(size_t)(LK-1)*NN] = 0.f;
}

// ---------------- K7: merged spline evaluation ----------------
__device__ __forceinline__ float spline_pt(const float* __restrict__ y, const float* __restrict__ M,
                                           int LK, int l, int b, int c){
  float hh = 1.f/(LK-1);
  float q = (float)l * (1.f/(LL-1));
  int idx = (int)floorf(q*(LK-1));
  if(idx > LK-2) idx = LK-2;
  float s = q - idx*hh;
  float u = hh - s;
  const float* yb = y + ((size_t)b*LK + idx)*NN + c;
  const float* Mb = M + ((size_t)b*LK + idx)*NN + c;
  float yi = yb[0], yi1 = yb[NN], M0 = Mb[0], M1 = Mb[NN];
  float hh6 = hh*hh/6.f;
  return (M0*u*u*u + M1*s*s*s)*(1.f/(6.f*hh))
       + (yi  - M0*hh6)*(u*(1.f/hh))
       + (yi1 - M1*hh6)*(s*(1.f/hh));
}

__global__ void k_spline_eval2(const float* __restrict__ y64, const float* __restrict__ M64,
                               const float* __restrict__ y16, const float* __restrict__ M16,
                               float* __restrict__ a){
  int l = blockIdx.x, b = blockIdx.y, ch = blockIdx.z, c = threadIdx.x;
  float val = (ch == 0) ? spline_pt(y64, M64, 64, l, b, c)
                        : spline_pt(y16, M16, 16, l, b, c);
  a[(((size_t)b*3 + 1 + ch)*LL + l)*NN + c] = val;
}

// ---------------- K8: conv1d stride 4, kernel 4 ----------------
__global__ __launch_bounds__(128) void k_conv2(const float* __restrict__ tt, const float* __restrict__ w,
                                               const float* __restrict__ bias, float* __restrict__ t2){
  __shared__ float ts[4*NN];
  int j = blockIdx.x, b = blockIdx.y, o = threadIdx.x;
  for(int i=o;i<4*NN;i+=NN) ts[i] = tt[((size_t)b*64 + j*4)*NN + i];
  __syncthreads();
  float acc = bias[o];
  const float* wp = w + (size_t)o*NN*4;
  #pragma unroll 4
  for(int ci=0;ci<NN;ci++){
    acc = fmaf(ts[0*NN+ci], wp[ci*4+0], acc);
    acc = fmaf(ts[1*NN+ci], wp[ci*4+1], acc);
    acc = fmaf(ts[2*NN+ci], wp[ci*4+2], acc);
    acc = fmaf(ts[3*NN+ci], wp[ci*4+3], acc);
  }
  t2[((size_t)b*NN + o)*16 + j] = acc;
}

// ---------------- K_h1: stage-1 conv + GELU -> h1g bf16 [brel][l][n][c], no halo ----------------
__global__ __launch_bounds__(256) void k_h1(const float* __restrict__ a, int bbase,
    const float* __restrict__ w0, const float* __restrict__ b0,
    const float* __restrict__ w1, const float* __restrict__ b1,
    bf16* __restrict__ h1g){
  constexpr int AY = 10, AX = 36;   // valid 34 cols
  __shared__ alignas(16) float as[3][AY][AX];   // 4.3 KB
  int tid = threadIdx.x;
  int l0 = blockIdx.x*8, n0 = blockIdx.y*32, brel = blockIdx.z, b = bbase + brel;
  const float* ab = a + (size_t)b*3*LL*NN;
  float* asf = &as[0][0][0];
  for(int i=tid;i<3*AY*AX;i+=256){
    int ch = i/(AY*AX), rem = i%(AY*AX), yy = rem/AX, xx = rem%AX;
    int gl = l0 + yy - 1, gn = n0 + xx - 1;
    float v = 0.f;
    if(xx < 34 && gl >= 0 && gl < LL && gn >= 0 && gn < NN) v = ab[((size_t)ch*LL + gl)*NN + gn];
    asf[i] = v;
  }
  int c = tid & 31, qg = tid >> 5;
  float wr[3][3][3];
  #pragma unroll
  for(int ci=0;ci<3;ci++)
    #pragma unroll
    for(int dy=0;dy<3;dy++)
      #pragma unroll
      for(int dx=0;dx<3;dx++){
        float wv = 0.5f*w1[((c*3+ci)*3+dy)*3+dx];
        if(dy==1 && dx==1) wv += 0.5f*w0[c*3+ci];
        wr[ci][dy][dx] = wv;
      }
  float br = 0.5f*(b0[c] + b1[c]);
  __syncthreads();
  // 8 rows x 8 x-quads = 64 quads; qg strides 8 -> 8 iterations
  for(int q=qg; q<64; q+=8){
    int yy = q >> 3, x0q = (q & 7)*4;
    float win[3][3][6];
    #pragma unroll
    for(int ci=0;ci<3;ci++)
      #pragma unroll
      for(int dy=0;dy<3;dy++){
        float4 r4 = *(const float4*)&as[ci][yy+dy][x0q];
        float2 r2 = *(const float2*)&as[ci][yy+dy][x0q+4];
        win[ci][dy][0]=r4.x; win[ci][dy][1]=r4.y; win[ci][dy][2]=r4.z;
        win[ci][dy][3]=r4.w; win[ci][dy][4]=r2.x; win[ci][dy][5]=r2.y;
      }
    #pragma unroll
    for(int p=0;p<4;p++){
      float s = br;
      #pragma unroll
      for(int ci=0;ci<3;ci++)
        #pragma unroll
        for(int dy=0;dy<3;dy++)
          #pragma unroll
          for(int dx=0;dx<3;dx++)
            s = fmaf(wr[ci][dy][dx], win[ci][dy][p+dx], s);
      float val = s*0.5f*(1.f + erff(s*0.70710678118654752f));
      h1g[(((size_t)brel*LL + l0 + yy)*NN + n0 + x0q + p)*DMC + c] = __float2bfloat16(val);
    }
  }
}

// ---------------- K_h2: stage-2 conv over h1g tile + residual, in-place into a0 ----------------
__device__ __forceinline__ float2 bf2f2(unsigned u){
  float2 r;
  r.x = __uint_as_float(u << 16);
  r.y = __uint_as_float(u & 0xffff0000u);
  return r;
}

__global__ __launch_bounds__(256) void k_h2(const bf16* __restrict__ h1g, int bbase,
    const float* __restrict__ vwsT, const float* __restrict__ vb0, const float* __restrict__ vb1,
    float* __restrict__ a /* residual in, cot out (ch0) */){
  __shared__ unsigned h1s[10][34][17];   // bf16 pairs, stride 17 dwords -> conflict-free
  int tid = threadIdx.x;
  int l0 = blockIdx.x*8, n0 = blockIdx.y*32, brel = blockIdx.z, b = bbase + brel;
  const unsigned* hg = (const unsigned*)h1g;
  // stage 10x34 px x 16 dword-pairs, coalesced
  for(int i=tid;i<340*16;i+=256){
    int px = i >> 4, cp = i & 15;
    int yy = px/34, xx = px - yy*34;
    int gl = l0 + yy - 1, gn = n0 + xx - 1;
    unsigned u = 0;
    if(gl >= 0 && gl < LL && gn >= 0 && gn < NN)
      u = hg[(((size_t)brel*LL + gl)*NN + gn)*16 + cp];
    h1s[yy][xx][cp] = u;
  }
  __syncthreads();
  int oy = tid >> 5, ox = tid & 31;
  float acc = 0.f;
  #pragma unroll
  for(int dy=0;dy<3;dy++)
    #pragma unroll
    for(int dx=0;dx<3;dx++){
      const unsigned* hp = &h1s[oy+dy][ox+dx][0];
      const float4* wt = (const float4*)(vwsT + (dy*3+dx)*DMC);
      #pragma unroll
      for(int cg=0;cg<8;cg++){
        unsigned u0 = hp[cg*2], u1 = hp[cg*2+1];
        float2 f0 = bf2f2(u0), f1 = bf2f2(u1);
        float4 wv = wt[cg];
        acc = fmaf(f0.x, wv.x, acc);
        acc = fmaf(f0.y, wv.y, acc);
        acc = fmaf(f1.x, wv.z, acc);
        acc = fmaf(f1.y, wv.w, acc);
      }
    }
  size_t idx = ((size_t)b*3*LL + l0 + oy)*NN + n0 + ox;
  a[idx] = acc + vb0[0] + vb1[0] + a[idx];
}

// ---------------- K15: tiled GEMM2 (A from a0/cot, stride 3*LL) + de-normalize ----------------
__global__ __launch_bounds__(256) void k_gemm2(const float* __restrict__ a, const float* __restrict__ ldw,
    const float* __restrict__ ldb, const float* __restrict__ sp, const float* __restrict__ s2p,
    float* __restrict__ out){
  __shared__ alignas(16) float As[16][68];
  __shared__ alignas(16) float Bs[16][68];
  int tid = threadIdx.x;
  int row0 = blockIdx.x*64, p0 = blockIdx.y*64;
  int b = row0 >> 7, n0 = row0 & 127;
  float acc[4][4] = {};
  int ar = tid & 63, ak = tid >> 6;
  int lk = tid & 15, lr = tid >> 4;
  int tr = tid & 15, tc = tid >> 4;
  for(int k0=0;k0<LL;k0+=16){
    #pragma unroll
    for(int q=0;q<4;q++){
      int k = ak*4 + q;
      As[k][ar] = a[((size_t)b*3*LL + k0 + k)*NN + n0 + ar];
    }
    #pragma unroll
    for(int q=0;q<4;q++){
      int cc = lr + 16*q;
      Bs[lk][cc] = ldw[(size_t)(p0+cc)*LL + k0 + lk];
    }
    __syncthreads();
    #pragma unroll
    for(int kk=0;kk<16;kk++){
      float4 av = *(const float4*)&As[kk][4*tr];
      float4 bv = *(const float4*)&Bs[kk][4*tc];
      float aa[4] = {av.x, av.y, av.z, av.w};
      float bb[4] = {bv.x, bv.y, bv.z, bv.w};
      #pragma unroll
      for(int i=0;i<4;i++)
        #pragma unroll
        for(int j=0;j<4;j++) acc[i][j] = fmaf(aa[i], bb[j], acc[i][j]);
    }
    __syncthreads();
  }
  #pragma unroll
  for(int i=0;i<4;i++){
    int row = row0 + 4*tr + i;
    int bb2 = row >> 7, n = row & 127;
    float ssum = 0.f, s2sum = 0.f;
    #pragma unroll
    for(int tq=0;tq<4;tq++){ ssum += sp[tq*2048 + row]; s2sum += s2p[tq*2048 + row]; }
    float mu = ssum*(1.f/512.f);
    float var = fmaxf(s2sum*(1.f/512.f) - mu*mu, 0.f);
    float sd = sqrtf(var + EPSF);
    #pragma unroll
    for(int j=0;j<4;j++){
      int p = p0 + 4*tc + j;
      float v = (acc[i][j] + ldb[p])*sd + mu;
      out[((size_t)bb2*PREDN + p)*NN + n] = v;
    }
  }
}

extern "C" void kernel_launch(void* const* d_in, const int* in_sizes, int n_in,
                              void* d_out, int out_size, void* d_ws, size_t ws_size,
                              hipStream_t stream){
  (void)in_sizes; (void)n_in; (void)out_size; (void)ws_size;
  const float* batch_x = (const float*)d_in[0];
  const float* le_w  = (const float*)d_in[4];
  const float* le_b  = (const float*)d_in[5];
  const float* c1_w  = (const float*)d_in[6];
  const float* c1_b  = (const float*)d_in[7];
  const float* bn1_g = (const float*)d_in[8];
  const float* bn1_b = (const float*)d_in[9];
  const float* c2_w  = (const float*)d_in[10];
  const float* c2_b  = (const float*)d_in[11];
  const float* bn2_g = (const float*)d_in[12];
  const float* bn2_b = (const float*)d_in[13];
  const float* i1_w0 = (const float*)d_in[14];
  const float* i1_b0 = (const float*)d_in[15];
  const float* i1_w1 = (const float*)d_in[16];
  const float* i1_b1 = (const float*)d_in[17];
  const float* i2_w0 = (const float*)d_in[18];
  const float* i2_b0 = (const float*)d_in[19];
  const float* i2_w1 = (const float*)d_in[20];
  const float* i2_b1 = (const float*)d_in[21];
  const float* ld_w  = (const float*)d_in[22];
  const float* ld_b  = (const float*)d_in[23];
  float* out = (float*)d_out;

  float* ws   = (float*)d_ws;
  float* sp   = ws;                       // 8192
  float* s2p  = sp + 8192;                // 8192
  float* vwsT = s2p + 8192;               // 288 (+pad)
  float* x    = vwsT + 320;               // 1,572,864
  float* a    = x + (size_t)BB*NN*LL;     // 4,718,592
  float* t1   = a + (size_t)BB*3*LL*NN;   // 131,072
  float* t1t  = t1 + (size_t)BB*NN*64;    // 131,072
  float* sc1  = t1t + (size_t)BB*64*NN;   // 128
  float* sh1  = sc1 + NN;                 // 128
  float* Msp1 = sh1 + NN;                 // 131,072
  float* t2   = Msp1 + (size_t)BB*64*NN;  // 32,768
  float* t2t  = t2 + (size_t)BB*NN*16;    // 32,768
  float* sc2  = t2t + (size_t)BB*16*NN;   // 128
  float* sh2  = sc2 + NN;                 // 128
  float* Msp2 = sh2 + NN;                 // 32,768
  bf16*  h1g  = (bf16*)(Msp2 + (size_t)BB*16*NN);  // 4*768*128*32 bf16 = 25.2 MB
  float* a0   = a;

  k_pre<<<65, 128, 0, stream>>>(batch_x, i2_w0, i2_w1, sp, s2p, vwsT);
  k_gemm1<<<dim3(32,12), 256, 0, stream>>>(batch_x, le_w, le_b, sp, s2p, x, a0);
  k_conv1<<<dim3(64,BB), NN, 0, stream>>>(x, c1_w, c1_b, t1);
  k_bnstats<<<NN, 256, 0, stream>>>(t1, bn1_g, bn1_b, BB, 64, sc1, sh1);
  k_bnelu_t<<<dim3(64,BB), NN, 0, stream>>>(t1, sc1, sh1, 64, t1t);
  k_spline_solve<64><<<BB, NN, 0, stream>>>(t1t, Msp1);
  k_conv2<<<dim3(16,BB), NN, 0, stream>>>(t1t, c2_w, c2_b, t2);
  k_bnstats<<<NN, 256, 0, stream>>>(t2, bn2_g, bn2_b, BB, 16, sc2, sh2);
  k_bnelu_t<<<dim3(16,BB), NN, 0, stream>>>(t2, sc2, sh2, 16, t2t);
  k_spline_solve<16><<<BB, NN, 0, stream>>>(t2t, Msp2);
  k_spline_eval2<<<dim3(LL,BB,2), NN, 0, stream>>>(t1t, Msp1, t2t, Msp2, a);
  for(int g=0; g<BB; g+=4){
    k_h1<<<dim3(96,4,4), 256, 0, stream>>>(a, g, i1_w0, i1_b0, i1_w1, i1_b1, h1g);
    k_h2<<<dim3(96,4,4), 256, 0, stream>>>(h1g, g, vwsT, i2_b0, i2_b1, a);
  }
  k_gemm2<<<dim3(32,4), 256, 0, stream>>>(a, ld_w, ld_b, sp, s2p, out);
}

// Round 11
// 392.183 us; speedup vs baseline: 1.5671x; 1.1408x over previous
//
#include <hip/hip_runtime.h>
#include <hip/hip_bf16.h>
#include <math.h>

#define BB 16
#define TT 512
#define NN 128
#define PREDN 256
#define DMC 32
#define LL 768
constexpr float EPSF = 1e-5f;
using bf16 = __hip_bfloat16;

// ---------------- K_pre: stats partials + weight fold + conv weight transposes ----------------
// blocks 0..63: stats; 64: vws fold; 65..192: c1_w transpose; 193..320: c2_w transpose
__global__ void k_pre(const float* __restrict__ bx, const float* __restrict__ v0,
                      const float* __restrict__ v1, const float* __restrict__ w1c,
                      const float* __restrict__ w2c, float* __restrict__ sp,
                      float* __restrict__ s2p, float* __restrict__ vwsT,
                      float* __restrict__ wT1, float* __restrict__ wT2){
  int blk = blockIdx.x;
  if(blk < 64){
    int b = blk >> 2, tq = blk & 3, n = threadIdx.x;
    const float* p = bx + (size_t)b*TT*NN + (size_t)tq*128*NN + n;
    float s = 0.f, s2 = 0.f;
    for(int t=0;t<128;t++){ float v = p[(size_t)t*NN]; s += v; s2 += v*v; }
    sp[tq*2048 + b*NN + n] = s;
    s2p[tq*2048 + b*NN + n] = s2;
  } else if(blk == 64){
    for(int i=threadIdx.x; i<9*DMC; i+=blockDim.x){
      int tap = i/DMC, c = i%DMC;
      float wv = 0.5f*v1[c*9 + tap];
      if(tap == 4) wv += 0.5f*v0[c];
      vwsT[i] = wv;
    }
  } else if(blk <= 192){
    int o = blk - 65;
    for(int k=threadIdx.x; k<1536; k+=blockDim.x)
      wT1[(size_t)k*NN + o] = w1c[(size_t)o*1536 + k];
  } else {
    int o = blk - 193;
    for(int k=threadIdx.x; k<512; k+=blockDim.x)
      wT2[(size_t)k*NN + o] = w2c[(size_t)o*512 + k];
  }
}

// ---------------- K1: tiled GEMM1 with fused normalization + dual store ----------------
__global__ __launch_bounds__(256) void k_gemm1(const float* __restrict__ bx, const float* __restrict__ lew,
    const float* __restrict__ leb, const float* __restrict__ sp, const float* __restrict__ s2p,
    float* __restrict__ x, float* __restrict__ a0){
  __shared__ alignas(16) float As[16][68];
  __shared__ alignas(16) float Bs[16][68];
  int tid = threadIdx.x;
  int row0 = blockIdx.x*64, l0 = blockIdx.y*64;
  int b = row0 >> 7, n0 = row0 & 127;
  float acc[4][4] = {};
  int ar = tid & 63, ak = tid >> 6;
  int bk = tid & 15, bc = tid >> 4;
  int tr = tid & 15, tc = tid >> 4;
  int rowa = row0 + ar;
  float ssum = 0.f, s2sum = 0.f;
  #pragma unroll
  for(int tq=0;tq<4;tq++){ ssum += sp[tq*2048 + rowa]; s2sum += s2p[tq*2048 + rowa]; }
  float mu_a = ssum*(1.f/512.f);
  float rs_a = 1.f/sqrtf(fmaxf(s2sum*(1.f/512.f) - mu_a*mu_a, 0.f) + EPSF);
  for(int k0=0;k0<TT;k0+=16){
    #pragma unroll
    for(int q=0;q<4;q++){
      int k = ak*4 + q;
      As[k][ar] = (bx[((size_t)b*TT + k0 + k)*NN + n0 + ar] - mu_a)*rs_a;
    }
    #pragma unroll
    for(int q=0;q<4;q++){
      int c = bc + 16*q;
      Bs[bk][c] = lew[(size_t)(l0+c)*TT + k0 + bk];
    }
    __syncthreads();
    #pragma unroll
    for(int kk=0;kk<16;kk++){
      float4 av = *(const float4*)&As[kk][4*tr];
      float4 bv = *(const float4*)&Bs[kk][4*tc];
      float aa[4] = {av.x, av.y, av.z, av.w};
      float bb[4] = {bv.x, bv.y, bv.z, bv.w};
      #pragma unroll
      for(int i=0;i<4;i++)
        #pragma unroll
        for(int j=0;j<4;j++) acc[i][j] = fmaf(aa[i], bb[j], acc[i][j]);
    }
    __syncthreads();
  }
  #pragma unroll
  for(int i=0;i<4;i++){
    int row = row0 + 4*tr + i;
    int l = l0 + 4*tc;
    float4 st;
    st.x = acc[i][0] + leb[l+0];
    st.y = acc[i][1] + leb[l+1];
    st.z = acc[i][2] + leb[l+2];
    st.w = acc[i][3] + leb[l+3];
    *(float4*)&x[(size_t)row*LL + l] = st;
  }
  #pragma unroll
  for(int j=0;j<4;j++){
    int l = l0 + 4*tc + j;
    float lb = leb[l];
    float4 st;
    st.x = acc[0][j] + lb;
    st.y = acc[1][j] + lb;
    st.z = acc[2][j] + lb;
    st.w = acc[3][j] + lb;
    *(float4*)&a0[((size_t)b*3*LL + l)*NN + n0 + 4*tr] = st;
  }
}

// ---------------- K3: conv1 (coalesced wT, 4 j per block) ----------------
__global__ __launch_bounds__(512) void k_conv1(const float* __restrict__ x, const float* __restrict__ wT,
                                               const float* __restrict__ bias, float* __restrict__ t1){
  __shared__ alignas(16) float xs[NN*48];
  int jt = blockIdx.x, b = blockIdx.y;
  int tid = threadIdx.x;
  int o = tid & 127, jj = tid >> 7;
  for(int i=tid;i<NN*48;i+=512){
    int ci = i/48, kk = i%48;
    xs[i] = x[((size_t)b*NN + ci)*LL + jt*48 + kk];
  }
  __syncthreads();
  float a0 = 0.f, a1 = 0.f, a2 = 0.f, a3 = 0.f;
  for(int ci=0;ci<NN;ci++){
    const float* xc = xs + ci*48 + jj*12;
    const float* wc = wT + (size_t)(ci*12)*NN + o;
    #pragma unroll
    for(int kk=0;kk<12;kk+=4){
      a0 = fmaf(xc[kk+0], wc[(size_t)(kk+0)*NN], a0);
      a1 = fmaf(xc[kk+1], wc[(size_t)(kk+1)*NN], a1);
      a2 = fmaf(xc[kk+2], wc[(size_t)(kk+2)*NN], a2);
      a3 = fmaf(xc[kk+3], wc[(size_t)(kk+3)*NN], a3);
    }
  }
  int j = jt*4 + jj;
  t1[((size_t)b*NN + o)*64 + j] = (a0 + a1) + (a2 + a3) + bias[o];
}

// ---------------- K4: BN stats per channel ----------------
__global__ void k_bnstats(const float* __restrict__ t, const float* __restrict__ g, const float* __restrict__ bb,
                          int Bcnt, int Jcnt, float* __restrict__ scale, float* __restrict__ shift){
  int o = blockIdx.x;
  int tot = Bcnt*Jcnt;
  float s = 0.f, s2 = 0.f;
  for(int i=threadIdx.x; i<tot; i+=blockDim.x){
    int b = i / Jcnt, j = i % Jcnt;
    float v = t[((size_t)b*NN + o)*Jcnt + j];
    s += v; s2 += v*v;
  }
  __shared__ float rs[256], rs2[256];
  rs[threadIdx.x] = s; rs2[threadIdx.x] = s2;
  __syncthreads();
  for(int st=128; st>0; st>>=1){
    if(threadIdx.x < st){ rs[threadIdx.x] += rs[threadIdx.x+st]; rs2[threadIdx.x] += rs2[threadIdx.x+st]; }
    __syncthreads();
  }
  if(threadIdx.x == 0){
    float mu = rs[0]/tot;
    float var = fmaxf(rs2[0]/tot - mu*mu, 0.f);
    float sc = g[o] * rsqrtf(var + EPSF);
    scale[o] = sc; shift[o] = bb[o] - mu*sc;
  }
}

// ---------------- K5: BN apply + ELU + transpose ----------------
__global__ void k_bnelu_t(const float* __restrict__ t, const float* __restrict__ scale,
                          const float* __restrict__ shift, int Jcnt, float* __restrict__ tt){
  int j = blockIdx.x, b = blockIdx.y, o = threadIdx.x;
  float v = t[((size_t)b*NN + o)*Jcnt + j]*scale[o] + shift[o];
  v = v > 0.f ? v : (expf(v) - 1.f);
  tt[((size_t)b*Jcnt + j)*NN + o] = v;
}

// ---------------- K6: spline tridiagonal solve (Thomas) ----------------
template<int LK>
__global__ void k_spline_solve(const float* __restrict__ y, float* __restrict__ M){
  constexpr int m = LK-2;
  const float Kc = 6.f*(LK-1)*(LK-1);
  __shared__ float cp[m];
  __shared__ float dp[m][NN];
  int b = blockIdx.x, c = threadIdx.x;
  if(c == 0){
    float cv = 0.25f; cp[0] = cv;
    for(int i=1;i<m;i++){ cv = 1.f/(4.f - cv); cp[i] = cv; }
  }
  __syncthreads();
  const float* yb = y + (size_t)b*LK*NN + c;
  float y0 = yb[0], y1 = yb[NN];
  float dprev = 0.f;
  for(int i=0;i<m;i++){
    float y2 = yb[(size_t)(i+2)*NN];
    float r = (y2 - 2.f*y1 + y0)*Kc;
    float d = (i == 0) ? r*0.25f : (r - dprev)*cp[i];
    dp[i][c] = d; dprev = d;
    y0 = y1; y1 = y2;
  }
  float* Mb = M + (size_t)b*LK*NN + c;
  float xv = dp[m-1][c];
  Mb[(size_t)m*NN] = xv;
  for(int i=m-2;i>=0;i--){
    xv = dp[i][c] - cp[i]*xv;
    Mb[(size_t)(i+1)*NN] = xv;
  }
  Mb[0] = 0.f;
  Mb[(size_t)(LK-1)*NN] = 0.f;
}

// ---------------- K7: merged spline evaluation ----------------
__device__ __forceinline__ float spline_pt(const float* __restrict__ y, const float* __restrict__ M,
                                           int LK, int l, int b, int c){
  float hh = 1.f/(LK-1);
  float q = (float)l * (1.f/(LL-1));
  int idx = (int)floorf(q*(LK-1));
  if(idx > LK-2) idx = LK-2;
  float s = q - idx*hh;
  float u = hh - s;
  const float* yb = y + ((size_t)b*LK + idx)*NN + c;
  const float* Mb = M + ((size_t)b*LK + idx)*NN + c;
  float yi = yb[0], yi1 = yb[NN], M0 = Mb[0], M1 = Mb[NN];
  float hh6 = hh*hh/6.f;
  return (M0*u*u*u + M1*s*s*s)*(1.f/(6.f*hh))
       + (yi  - M0*hh6)*(u*(1.f/hh))
       + (yi1 - M1*hh6)*(s*(1.f/hh));
}

__global__ void k_spline_eval2(const float* __restrict__ y64, const float* __restrict__ M64,
                               const float* __restrict__ y16, const float* __restrict__ M16,
                               float* __restrict__ a){
  int l = blockIdx.x, b = blockIdx.y, ch = blockIdx.z, c = threadIdx.x;
  float val = (ch == 0) ? spline_pt(y64, M64, 64, l, b, c)
                        : spline_pt(y16, M16, 16, l, b, c);
  a[(((size_t)b*3 + 1 + ch)*LL + l)*NN + c] = val;
}

// ---------------- K8: conv2 (coalesced wT, 4 j per block) ----------------
__global__ __launch_bounds__(512) void k_conv2(const float* __restrict__ tt, const float* __restrict__ wT,
                                               const float* __restrict__ bias, float* __restrict__ t2){
  __shared__ alignas(16) float ts[16*NN];   // [li][ci]
  int jt = blockIdx.x, b = blockIdx.y;
  int tid = threadIdx.x;
  int o = tid & 127, jj = tid >> 7;
  for(int i=tid;i<16*NN;i+=512)
    ts[i] = tt[((size_t)b*64 + jt*16)*NN + i];
  __syncthreads();
  float a0 = 0.f, a1 = 0.f, a2 = 0.f, a3 = 0.f;
  for(int ci=0;ci<NN;ci++){
    const float* wc = wT + (size_t)(ci*4)*NN + o;
    const float* tc2 = ts + (jj*4)*NN + ci;
    a0 = fmaf(tc2[0*NN], wc[0*NN], a0);
    a1 = fmaf(tc2[1*NN], wc[1*NN], a1);
    a2 = fmaf(tc2[2*NN], wc[2*NN], a2);
    a3 = fmaf(tc2[3*NN], wc[3*NN], a3);
  }
  int j = jt*4 + jj;
  t2[((size_t)b*NN + o)*16 + j] = (a0 + a1) + (a2 + a3) + bias[o];
}

// ---------------- K_h1: stage-1 conv + GELU -> h1g bf16 [brel][l][n][c] ----------------
__global__ __launch_bounds__(256) void k_h1(const float* __restrict__ a, int bbase,
    const float* __restrict__ w0, const float* __restrict__ b0,
    const float* __restrict__ w1, const float* __restrict__ b1,
    bf16* __restrict__ h1g){
  constexpr int AY = 10, AX = 36;
  __shared__ alignas(16) float as[3][AY][AX];
  int tid = threadIdx.x;
  int l0 = blockIdx.x*8, n0 = blockIdx.y*32, brel = blockIdx.z, b = bbase + brel;
  const float* ab = a + (size_t)b*3*LL*NN;
  float* asf = &as[0][0][0];
  for(int i=tid;i<3*AY*AX;i+=256){
    int ch = i/(AY*AX), rem = i%(AY*AX), yy = rem/AX, xx = rem%AX;
    int gl = l0 + yy - 1, gn = n0 + xx - 1;
    float v = 0.f;
    if(xx < 34 && gl >= 0 && gl < LL && gn >= 0 && gn < NN) v = ab[((size_t)ch*LL + gl)*NN + gn];
    asf[i] = v;
  }
  int c = tid & 31, qg = tid >> 5;
  float wr[3][3][3];
  #pragma unroll
  for(int ci=0;ci<3;ci++)
    #pragma unroll
    for(int dy=0;dy<3;dy++)
      #pragma unroll
      for(int dx=0;dx<3;dx++){
        float wv = 0.5f*w1[((c*3+ci)*3+dy)*3+dx];
        if(dy==1 && dx==1) wv += 0.5f*w0[c*3+ci];
        wr[ci][dy][dx] = wv;
      }
  float br = 0.5f*(b0[c] + b1[c]);
  __syncthreads();
  for(int q=qg; q<64; q+=8){
    int yy = q >> 3, x0q = (q & 7)*4;
    float win[3][3][6];
    #pragma unroll
    for(int ci=0;ci<3;ci++)
      #pragma unroll
      for(int dy=0;dy<3;dy++){
        float4 r4 = *(const float4*)&as[ci][yy+dy][x0q];
        float2 r2 = *(const float2*)&as[ci][yy+dy][x0q+4];
        win[ci][dy][0]=r4.x; win[ci][dy][1]=r4.y; win[ci][dy][2]=r4.z;
        win[ci][dy][3]=r4.w; win[ci][dy][4]=r2.x; win[ci][dy][5]=r2.y;
      }
    #pragma unroll
    for(int p=0;p<4;p++){
      float s = br;
      #pragma unroll
      for(int ci=0;ci<3;ci++)
        #pragma unroll
        for(int dy=0;dy<3;dy++)
          #pragma unroll
          for(int dx=0;dx<3;dx++)
            s = fmaf(wr[ci][dy][dx], win[ci][dy][p+dx], s);
      float val = s*0.5f*(1.f + erff(s*0.70710678118654752f));
      h1g[(((size_t)brel*LL + l0 + yy)*NN + n0 + x0q + p)*DMC + c] = __float2bfloat16(val);
    }
  }
}

// ---------------- K_h2: stage-2 conv + residual, in-place into a0 ----------------
__device__ __forceinline__ float2 bf2f2(unsigned u){
  float2 r;
  r.x = __uint_as_float(u << 16);
  r.y = __uint_as_float(u & 0xffff0000u);
  return r;
}

__global__ __launch_bounds__(256) void k_h2(const bf16* __restrict__ h1g, int bbase,
    const float* __restrict__ vwsT, const float* __restrict__ vb0, const float* __restrict__ vb1,
    float* __restrict__ a){
  __shared__ unsigned h1s[10][34][17];
  int tid = threadIdx.x;
  int l0 = blockIdx.x*8, n0 = blockIdx.y*32, brel = blockIdx.z, b = bbase + brel;
  const unsigned* hg = (const unsigned*)h1g;
  for(int i=tid;i<340*16;i+=256){
    int px = i >> 4, cp = i & 15;
    int yy = px/34, xx = px - yy*34;
    int gl = l0 + yy - 1, gn = n0 + xx - 1;
    unsigned u = 0;
    if(gl >= 0 && gl < LL && gn >= 0 && gn < NN)
      u = hg[(((size_t)brel*LL + gl)*NN + gn)*16 + cp];
    h1s[yy][xx][cp] = u;
  }
  __syncthreads();
  int oy = tid >> 5, ox = tid & 31;
  float acc = 0.f;
  #pragma unroll
  for(int dy=0;dy<3;dy++)
    #pragma unroll
    for(int dx=0;dx<3;dx++){
      const unsigned* hp = &h1s[oy+dy][ox+dx][0];
      const float4* wt = (const float4*)(vwsT + (dy*3+dx)*DMC);
      #pragma unroll
      for(int cg=0;cg<8;cg++){
        unsigned u0 = hp[cg*2], u1 = hp[cg*2+1];
        float2 f0 = bf2f2(u0), f1 = bf2f2(u1);
        float4 wv = wt[cg];
        acc = fmaf(f0.x, wv.x, acc);
        acc = fmaf(f0.y, wv.y, acc);
        acc = fmaf(f1.x, wv.z, acc);
        acc = fmaf(f1.y, wv.w, acc);
      }
    }
  size_t idx = ((size_t)b*3*LL + l0 + oy)*NN + n0 + ox;
  a[idx] = acc + vb0[0] + vb1[0] + a[idx];
}

// ---------------- K15: tiled GEMM2 (A from a0, stride 3*LL) + de-normalize ----------------
__global__ __launch_bounds__(256) void k_gemm2(const float* __restrict__ a, const float* __restrict__ ldw,
    const float* __restrict__ ldb, const float* __restrict__ sp, const float* __restrict__ s2p,
    float* __restrict__ out){
  __shared__ alignas(16) float As[16][68];
  __shared__ alignas(16) float Bs[16][68];
  int tid = threadIdx.x;
  int row0 = blockIdx.x*64, p0 = blockIdx.y*64;
  int b = row0 >> 7, n0 = row0 & 127;
  float acc[4][4] = {};
  int ar = tid & 63, ak = tid >> 6;
  int lk = tid & 15, lr = tid >> 4;
  int tr = tid & 15, tc = tid >> 4;
  for(int k0=0;k0<LL;k0+=16){
    #pragma unroll
    for(int q=0;q<4;q++){
      int k = ak*4 + q;
      As[k][ar] = a[((size_t)b*3*LL + k0 + k)*NN + n0 + ar];
    }
    #pragma unroll
    for(int q=0;q<4;q++){
      int cc = lr + 16*q;
      Bs[lk][cc] = ldw[(size_t)(p0+cc)*LL + k0 + lk];
    }
    __syncthreads();
    #pragma unroll
    for(int kk=0;kk<16;kk++){
      float4 av = *(const float4*)&As[kk][4*tr];
      float4 bv = *(const float4*)&Bs[kk][4*tc];
      float aa[4] = {av.x, av.y, av.z, av.w};
      float bb[4] = {bv.x, bv.y, bv.z, bv.w};
      #pragma unroll
      for(int i=0;i<4;i++)
        #pragma unroll
        for(int j=0;j<4;j++) acc[i][j] = fmaf(aa[i], bb[j], acc[i][j]);
    }
    __syncthreads();
  }
  #pragma unroll
  for(int i=0;i<4;i++){
    int row = row0 + 4*tr + i;
    int bb2 = row >> 7, n = row & 127;
    float ssum = 0.f, s2sum = 0.f;
    #pragma unroll
    for(int tq=0;tq<4;tq++){ ssum += sp[tq*2048 + row]; s2sum += s2p[tq*2048 + row]; }
    float mu = ssum*(1.f/512.f);
    float var = fmaxf(s2sum*(1.f/512.f) - mu*mu, 0.f);
    float sd = sqrtf(var + EPSF);
    #pragma unroll
    for(int j=0;j<4;j++){
      int p = p0 + 4*tc + j;
      float v = (acc[i][j] + ldb[p])*sd + mu;
      out[((size_t)bb2*PREDN + p)*NN + n] = v;
    }
  }
}

extern "C" void kernel_launch(void* const* d_in, const int* in_sizes, int n_in,
                              void* d_out, int out_size, void* d_ws, size_t ws_size,
                              hipStream_t stream){
  (void)in_sizes; (void)n_in; (void)out_size; (void)ws_size;
  const float* batch_x = (const float*)d_in[0];
  const float* le_w  = (const float*)d_in[4];
  const float* le_b  = (const float*)d_in[5];
  const float* c1_w  = (const float*)d_in[6];
  const float* c1_b  = (const float*)d_in[7];
  const float* bn1_g = (const float*)d_in[8];
  const float* bn1_b = (const float*)d_in[9];
  const float* c2_w  = (const float*)d_in[10];
  const float* c2_b  = (const float*)d_in[11];
  const float* bn2_g = (const float*)d_in[12];
  const float* bn2_b = (const float*)d_in[13];
  const float* i1_w0 = (const float*)d_in[14];
  const float* i1_b0 = (const float*)d_in[15];
  const float* i1_w1 = (const float*)d_in[16];
  const float* i1_b1 = (const float*)d_in[17];
  const float* i2_w0 = (const float*)d_in[18];
  const float* i2_b0 = (const float*)d_in[19];
  const float* i2_w1 = (const float*)d_in[20];
  const float* i2_b1 = (const float*)d_in[21];
  const float* ld_w  = (const float*)d_in[22];
  const float* ld_b  = (const float*)d_in[23];
  float* out = (float*)d_out;

  float* ws   = (float*)d_ws;
  float* sp   = ws;                        // 8192
  float* s2p  = sp + 8192;                 // 8192
  float* vwsT = s2p + 8192;                // 288 (+pad)
  float* wT1  = vwsT + 320;                // 1536*128 = 196,608
  float* wT2  = wT1 + 196608;              // 512*128 = 65,536
  float* x    = wT2 + 65536;               // 1,572,864
  float* a    = x + (size_t)BB*NN*LL;      // 4,718,592
  float* t1   = a + (size_t)BB*3*LL*NN;    // 131,072
  float* t1t  = t1 + (size_t)BB*NN*64;     // 131,072
  float* sc1  = t1t + (size_t)BB*64*NN;    // 128
  float* sh1  = sc1 + NN;                  // 128
  float* Msp1 = sh1 + NN;                  // 131,072
  float* t2   = Msp1 + (size_t)BB*64*NN;   // 32,768
  float* t2t  = t2 + (size_t)BB*NN*16;     // 32,768
  float* sc2  = t2t + (size_t)BB*16*NN;    // 128
  float* sh2  = sc2 + NN;                  // 128
  float* Msp2 = sh2 + NN;                  // 32,768
  bf16*  h1g  = (bf16*)(Msp2 + (size_t)BB*16*NN);  // 4*768*128*32 bf16 = 25.2 MB
  float* a0   = a;

  k_pre<<<321, 128, 0, stream>>>(batch_x, i2_w0, i2_w1, c1_w, c2_w, sp, s2p, vwsT, wT1, wT2);
  k_gemm1<<<dim3(32,12), 256, 0, stream>>>(batch_x, le_w, le_b, sp, s2p, x, a0);
  k_conv1<<<dim3(16,BB), 512, 0, stream>>>(x, wT1, c1_b, t1);
  k_bnstats<<<NN, 256, 0, stream>>>(t1, bn1_g, bn1_b, BB, 64, sc1, sh1);
  k_bnelu_t<<<dim3(64,BB), NN, 0, stream>>>(t1, sc1, sh1, 64, t1t);
  k_spline_solve<64><<<BB, NN, 0, stream>>>(t1t, Msp1);
  k_conv2<<<dim3(4,BB), 512, 0, stream>>>(t1t, wT2, c2_b, t2);
  k_bnstats<<<NN, 256, 0, stream>>>(t2, bn2_g, bn2_b, BB, 16, sc2, sh2);
  k_bnelu_t<<<dim3(16,BB), NN, 0, stream>>>(t2, sc2, sh2, 16, t2t);
  k_spline_solve<16><<<BB, NN, 0, stream>>>(t2t, Msp2);
  k_spline_eval2<<<dim3(LL,BB,2), NN, 0, stream>>>(t1t, Msp1, t2t, Msp2, a);
  for(int g=0; g<BB; g+=4){
    k_h1<<<dim3(96,4,4), 256, 0, stream>>>(a, g, i1_w0, i1_b0, i1_w1, i1_b1, h1g);
    k_h2<<<dim3(96,4,4), 256, 0, stream>>>(h1g, g, vwsT, i2_b0, i2_b1, a);
  }
  k_gemm2<<<dim3(32,4), 256, 0, stream>>>(a, ld_w, ld_b, sp, s2p, out);
}